// Round 11
// baseline (68.714 us; speedup 1.0000x reference)
//
#include <hip/hip_runtime.h>

// CRF NLL forward, B=8192, L=512, T=6 (4 real states + START/STOP).
// One wave per batch. Lane l builds the ordered product of M_l for its 8
// contiguous steps (M = diag(exp(feat)) * E, scaled-probability domain,
// power-of-2 renorm, exponent in an int). Combine: 6-round ordered
// __shfl_down reduction (P <- P_{lane+k} * P_lane; lane 0 ends with the
// full 512-step product). Gold fused per-lane and shuffle-reduced.
// R11: all 4x4 matmuls packed as <2 x float> ops -> v_pk_fma_f32 (CDNA
// full-rate packed FP32), halving the dominant VALU stream. P stored as
// 8 float2 (row i, col-pair jp). Combine renorm reduced to one (k==4).

#define BB 8192
#define LL 512
#define LN2F 0.69314718055994530942f

typedef float f32x2 __attribute__((ext_vector_type(2)));

__device__ __forceinline__ f32x2 sp2(float s) { return (f32x2){s, s}; }
__device__ __forceinline__ f32x2 fma2(f32x2 a, f32x2 b, f32x2 c) {
    return __builtin_elementwise_fma(a, b, c);
}

__device__ __forceinline__ float uniformf(float x) {
    return __uint_as_float(__builtin_amdgcn_readfirstlane(__float_as_uint(x)));
}

// Renorm P2[8] by exponent of max entry (exact power of 2).
#define RENORM2(P2, MEX)                                                \
  do {                                                                  \
    f32x2 m2_ = __builtin_elementwise_max(P2[0], P2[1]);                \
    _Pragma("unroll")                                                   \
    for (int z_ = 2; z_ < 8; ++z_)                                      \
        m2_ = __builtin_elementwise_max(m2_, P2[z_]);                   \
    const float m_ = fmaxf(m2_.x, m2_.y);                               \
    const int ee_ = (int)((__float_as_uint(m_) >> 23) & 255) - 127;     \
    const f32x2 sc_ = sp2(__uint_as_float((unsigned)(127 - ee_) << 23));\
    _Pragma("unroll") for (int z_ = 0; z_ < 8; ++z_) P2[z_] *= sc_;     \
    MEX += ee_;                                                         \
  } while (0)

// One leaf step for r>=1: P <- diag(exp(f)) * E * P (masked), fused gold.
// P2[i*2+jp] = (row i, cols {2jp, 2jp+1}).
#define STEP(R, F0, F1, F2, F3)                                         \
  do {                                                                  \
    const bool act_ = (base + (R)) < len;                               \
    const float f0_=(F0), f1_=(F1), f2_=(F2), f3_=(F3);                 \
    const float fes_[4] = { __expf(f0_), __expf(f1_),                   \
                            __expf(f2_), __expf(f3_) };                 \
    f32x2 T2[8];                                                        \
    _Pragma("unroll")                                                   \
    for (int i = 0; i < 4; ++i)                                         \
      _Pragma("unroll")                                                 \
      for (int jp = 0; jp < 2; ++jp)                                    \
        T2[i*2+jp] = fma2(sp2(E[i*4+0]), P2[0+jp],                      \
                     fma2(sp2(E[i*4+1]), P2[2+jp],                      \
                     fma2(sp2(E[i*4+2]), P2[4+jp],                      \
                          sp2(E[i*4+3]) * P2[6+jp])));                  \
    _Pragma("unroll")                                                   \
    for (int i = 0; i < 4; ++i)                                         \
      _Pragma("unroll")                                                 \
      for (int jp = 0; jp < 2; ++jp)                                    \
        P2[i*2+jp] = act_ ? sp2(fes_[i]) * T2[i*2+jp] : P2[i*2+jp];     \
    const int tg_ = tg##R;                                              \
    const float lut_ = sT[tg_ * 6 + tgp##R];                            \
    const float em_  = (tg_ & 2) ? ((tg_ & 1) ? f3_ : f2_)              \
                                 : ((tg_ & 1) ? f1_ : f0_);             \
    gold += act_ ? (lut_ + em_) : 0.f;                                  \
  } while (0)

__global__ __launch_bounds__(128, 8) void crf_tree(
    const float* __restrict__ feats,
    const float* __restrict__ trans,
    const int*   __restrict__ tags,
    const int*   __restrict__ lens,
    float* __restrict__ partials)
{
    __shared__ float sT[36];

    const int tid  = threadIdx.x;
    const int lane = tid & 63;
    const int wv   = tid >> 6;
    const int b    = blockIdx.x * 2 + wv;

    if (tid < 36) sT[tid] = trans[tid];
    __syncthreads();

    // wave-uniform transition constants (SGPR via readfirstlane)
    float E[16], e4[4], e5[4];
    #pragma unroll
    for (int i = 0; i < 16; ++i)
        E[i] = uniformf(__expf(sT[(i >> 2) * 6 + (i & 3)]));
    #pragma unroll
    for (int i = 0; i < 4; ++i) {
        e4[i] = uniformf(__expf(sT[i * 6 + 4]));   // exp(trans[i][START])
        e5[i] = uniformf(__expf(sT[30 + i]));      // exp(trans[STOP][i])
    }

    const int len  = lens[b];
    const int base = lane * 8;
    const bool lane0 = (lane == 0);

    // ---- loads: 4 used emission columns only (128B/lane) ----
    const float* fp = feats + (size_t)b * (LL * 6) + lane * 48;
    const float4 A0 = *(const float4*)(fp + 0);    // step 0: f0..f3
    const float2 A1 = *(const float2*)(fp + 6);    // step 1: f0,f1
    const float2 A2 = *(const float2*)(fp + 8);    // step 1: f2,f3
    const float4 B0 = *(const float4*)(fp + 12);   // step 2
    const float2 B1 = *(const float2*)(fp + 18);   // step 3
    const float2 B2 = *(const float2*)(fp + 20);
    const float4 C0 = *(const float4*)(fp + 24);   // step 4
    const float2 C1 = *(const float2*)(fp + 30);   // step 5
    const float2 C2 = *(const float2*)(fp + 32);
    const float4 D0 = *(const float4*)(fp + 36);   // step 6
    const float2 D1 = *(const float2*)(fp + 42);   // step 7
    const float2 D2 = *(const float2*)(fp + 44);

    const int* tbp = tags + (size_t)b * LL + base;
    const int4 ta  = *(const int4*)tbp;
    const int4 tb4 = *(const int4*)(tbp + 4);
    const int tg0=ta.x&3,  tg1=ta.y&3,  tg2=ta.z&3,  tg3=ta.w&3;
    const int tg4=tb4.x&3, tg5=tb4.y&3, tg6=tb4.z&3, tg7=tb4.w&3;
    const int ptail = __shfl_up(tg7, 1, 64);
    const int prev0 = lane0 ? 4 : ptail;
    const int tgp1=tg0, tgp2=tg1, tgp3=tg2,
              tgp4=tg3, tgp5=tg4, tgp6=tg5, tgp7=tg6;   // prev-tag per step

    // identity: row i, col-pair jp
    f32x2 P2[8];
    #pragma unroll
    for (int i = 0; i < 4; ++i)
        #pragma unroll
        for (int jp = 0; jp < 2; ++jp)
            P2[i*2+jp] = (f32x2){ (2*jp   == i) ? 1.f : 0.f,
                                  (2*jp+1 == i) ? 1.f : 0.f };
    int   mex  = 0;
    float gold = 0.f;

    // ---- step 0 specialized: P = diag(fe) * (lane0 ? e4-cols : E) ----
    {
        const bool act_ = base < len;
        const float f0_=A0.x, f1_=A0.y, f2_=A0.z, f3_=A0.w;
        const float fes_[4] = { __expf(f0_), __expf(f1_),
                                __expf(f2_), __expf(f3_) };
        #pragma unroll
        for (int i = 0; i < 4; ++i)
            #pragma unroll
            for (int jp = 0; jp < 2; ++jp) {
                const f32x2 base2 = lane0 ? sp2(e4[i])
                    : (f32x2){ E[i*4 + 2*jp], E[i*4 + 2*jp + 1] };
                P2[i*2+jp] = act_ ? sp2(fes_[i]) * base2 : P2[i*2+jp];
            }
        const float lut_ = sT[tg0 * 6 + prev0];
        const float em_  = (tg0 & 2) ? ((tg0 & 1) ? f3_ : f2_)
                                     : ((tg0 & 1) ? f1_ : f0_);
        gold += act_ ? (lut_ + em_) : 0.f;
    }
    STEP(1, A1.x, A1.y, A2.x, A2.y);
    STEP(2, B0.x, B0.y, B0.z, B0.w);
    STEP(3, B1.x, B1.y, B2.x, B2.y);
    RENORM2(P2, mex);
    STEP(4, C0.x, C0.y, C0.z, C0.w);
    STEP(5, C1.x, C1.y, C2.x, C2.y);
    STEP(6, D0.x, D0.y, D0.z, D0.w);
    STEP(7, D1.x, D1.y, D2.x, D2.y);
    RENORM2(P2, mex);

    // terminal gold: lane owning step len-1 adds trans[STOP][last_tag]
    {
        const unsigned dl = (unsigned)(len - 1 - base);
        if (dl < 8u) gold += sT[30 + (tbp[dl] & 3)];
    }

    // ---- ordered shfl_down reduction: lane 0 ends with P_63 ... P_0 ----
    // Every lane computes Q*P (Q = later segment from lane+k). High-lane
    // garbage is finite and harmless. One renorm (k==4): growth bound
    // 4*1024^2 ~ 4.2e6 per two un-renormed rounds, far below fp32 max.
    #pragma unroll
    for (int k = 1; k <= 32; k <<= 1) {
        f32x2 Q2[8];
        #pragma unroll
        for (int z = 0; z < 8; ++z)
            Q2[z] = (f32x2){ __shfl_down(P2[z].x, k, 64),
                             __shfl_down(P2[z].y, k, 64) };
        const int mq = __shfl_down(mex, k, 64);
        f32x2 N2[8];
        #pragma unroll
        for (int i = 0; i < 4; ++i)
            #pragma unroll
            for (int jp = 0; jp < 2; ++jp)
                N2[i*2+jp] = fma2(sp2(Q2[i*2+0].x), P2[0+jp],
                             fma2(sp2(Q2[i*2+0].y), P2[2+jp],
                             fma2(sp2(Q2[i*2+1].x), P2[4+jp],
                                  sp2(Q2[i*2+1].y) * P2[6+jp])));
        #pragma unroll
        for (int z = 0; z < 8; ++z) P2[z] = N2[z];
        mex += mq;
        if (k == 4) RENORM2(P2, mex);
    }

    // gold: sum across lanes
    #pragma unroll
    for (int k = 1; k <= 32; k <<= 1)
        gold += __shfl_xor(gold, k, 64);

    // lane 0: columns of P all equal alpha (e4 folded into lane 0's leaf)
    const float dot = fmaf(e5[0], P2[0].x, fmaf(e5[1], P2[2].x,
                      fmaf(e5[2], P2[4].x, e5[3] * P2[6].x)));
    const float logz = fmaf((float)mex, LN2F, __logf(dot));
    if (lane == 0)
        partials[b] = logz - gold;
}

__global__ __launch_bounds__(256) void k_reduce(const float* __restrict__ partials,
                                               float* __restrict__ out)
{
    __shared__ float sh[256];
    const int t = threadIdx.x;
    float s = 0.f;
    #pragma unroll
    for (int j = 0; j < 32; ++j) s += partials[t + 256 * j];
    sh[t] = s;
    __syncthreads();
    #pragma unroll
    for (int d = 128; d > 0; d >>= 1) {
        if (t < d) sh[t] += sh[t + d];
        __syncthreads();
    }
    if (t == 0) out[0] = sh[0] * (1.0f / 8192.0f);
}

extern "C" void kernel_launch(void* const* d_in, const int* in_sizes, int n_in,
                              void* d_out, int out_size, void* d_ws, size_t ws_size,
                              hipStream_t stream) {
    const float* feats = (const float*)d_in[0];
    const float* trans = (const float*)d_in[1];
    const int*   tags  = (const int*)d_in[2];
    const int*   lens  = (const int*)d_in[3];
    float* out = (float*)d_out;
    float* partials = (float*)d_ws;        // 8192 floats

    crf_tree<<<BB / 2, 128, 0, stream>>>(feats, trans, tags, lens, partials);
    k_reduce<<<1, 256, 0, stream>>>(partials, out);
}

// Round 12
// 46.240 us; speedup vs baseline: 1.4860x; 1.4860x over previous
//
#include <hip/hip_runtime.h>

// CRF NLL forward, B=8192, L=512, T=6 (4 real states + START/STOP).
// 64-lane wave = 4 batches x 16 lanes. Lane (g,c) builds the ordered product
// of M_l = diag(exp(feat_l)) * E over steps [32c, 32c+32) of batch g
// (scaled-probability domain, power-of-2 renorm every 4 steps, exponent in
// an int). Combine: 4 ordered __shfl_down rounds at width=16 (k=1,2,4,8);
// group-lane 0 ends with the full 512-step product. START folded into
// segment 0's first step; gold fused per-lane, shfl_xor-reduced in-group.
// Loads: only the 4 used emission columns (float4+2x float2 per 2 steps).
// R12: G=16 restructure cuts combine cost 630->105 wave-inst/batch.
// (R11 post-mortem: ext_vector f32x2 arrays spilled to scratch - 88 MB
// WRITE_SIZE; packed fp32 abandoned, all-scalar registers here.)

#define BB 8192
#define LL 512
#define LN2F 0.69314718055994530942f

__device__ __forceinline__ float uniformf(float x) {
    return __uint_as_float(__builtin_amdgcn_readfirstlane(__float_as_uint(x)));
}

#define RENORM16(P, MEX)                                                \
  do {                                                                  \
    float m_ = fmaxf(P[0], P[1]);                                       \
    _Pragma("unroll") for (int z_ = 2; z_ < 16; ++z_) m_ = fmaxf(m_, P[z_]); \
    const int ee_ = (int)((__float_as_uint(m_) >> 23) & 255) - 127;     \
    const float sc_ = __uint_as_float((unsigned)(127 - ee_) << 23);     \
    _Pragma("unroll") for (int z_ = 0; z_ < 16; ++z_) P[z_] *= sc_;     \
    MEX += ee_;                                                         \
  } while (0)

// One step at absolute index ABS: P <- diag(exp(f)) * E * P (masked), + gold.
#define STEP(ABS, F0, F1, F2, F3, TG, PV)                               \
  do {                                                                  \
    const bool act_ = (ABS) < len;                                      \
    const float f0_=(F0), f1_=(F1), f2_=(F2), f3_=(F3);                 \
    const float fe0_=__expf(f0_), fe1_=__expf(f1_);                     \
    const float fe2_=__expf(f2_), fe3_=__expf(f3_);                     \
    _Pragma("unroll")                                                   \
    for (int j = 0; j < 4; ++j) {                                       \
      const float c0_=P[0*4+j], c1_=P[1*4+j], c2_=P[2*4+j], c3_=P[3*4+j]; \
      const float t0_ = fmaf(E[0], c0_, fmaf(E[1], c1_, fmaf(E[2], c2_, E[3] *c3_))); \
      const float t1_ = fmaf(E[4], c0_, fmaf(E[5], c1_, fmaf(E[6], c2_, E[7] *c3_))); \
      const float t2_ = fmaf(E[8], c0_, fmaf(E[9], c1_, fmaf(E[10],c2_, E[11]*c3_))); \
      const float t3_ = fmaf(E[12],c0_, fmaf(E[13],c1_, fmaf(E[14],c2_, E[15]*c3_))); \
      P[0*4+j] = act_ ? fe0_*t0_ : P[0*4+j];                            \
      P[1*4+j] = act_ ? fe1_*t1_ : P[1*4+j];                            \
      P[2*4+j] = act_ ? fe2_*t2_ : P[2*4+j];                            \
      P[3*4+j] = act_ ? fe3_*t3_ : P[3*4+j];                            \
    }                                                                   \
    const float lut_ = sT[(TG) * 6 + (PV)];                             \
    const float em_  = ((TG) & 2) ? (((TG) & 1) ? f3_ : f2_)            \
                                  : (((TG) & 1) ? f1_ : f0_);           \
    gold += act_ ? (lut_ + em_) : 0.f;                                  \
  } while (0)

__global__ __launch_bounds__(256, 2) void crf_tree(
    const float* __restrict__ feats,
    const float* __restrict__ trans,
    const int*   __restrict__ tags,
    const int*   __restrict__ lens,
    float* __restrict__ partials)
{
    __shared__ float sT[36];

    const int tid  = threadIdx.x;
    const int lane = tid & 63;
    const int wv   = tid >> 6;
    const int g    = lane >> 4;        // batch sub-index within wave (0..3)
    const int c    = lane & 15;        // segment index within batch (0..15)
    const int b    = blockIdx.x * 16 + wv * 4 + g;

    if (tid < 36) sT[tid] = trans[tid];
    __syncthreads();

    // wave-uniform transition constants (SGPR via readfirstlane)
    float E[16], e4[4], e5[4];
    #pragma unroll
    for (int i = 0; i < 16; ++i)
        E[i] = uniformf(__expf(sT[(i >> 2) * 6 + (i & 3)]));
    #pragma unroll
    for (int i = 0; i < 4; ++i) {
        e4[i] = uniformf(__expf(sT[i * 6 + 4]));   // exp(trans[i][START])
        e5[i] = uniformf(__expf(sT[30 + i]));      // exp(trans[STOP][i])
    }

    const int len  = lens[b];
    const int base = c * 32;
    const bool seg0 = (c == 0);

    const float* fp  = feats + (size_t)b * (LL * 6) + (size_t)base * 6;
    const int*   tbp = tags  + (size_t)b * LL + base;

    // boundary prev-tag (segment 0 uses START=4); load exec-masked for c>0
    const int pv0 = seg0 ? 4 : (tbp[-1] & 3);

    float P[16];
    #pragma unroll
    for (int z = 0; z < 16; ++z) P[z] = (z % 5 == 0) ? 1.f : 0.f;
    int   mex  = 0;
    float gold = 0.f;
    int   pv;

    // ---- peeled first 4 steps (step base+0 specialized: P was identity) ----
    {
        const int4 tq = *(const int4*)tbp;
        const int t0 = tq.x & 3, t1 = tq.y & 3, t2 = tq.z & 3, t3 = tq.w & 3;
        const float4 a0 = *(const float4*)(fp + 0);
        const float2 a1 = *(const float2*)(fp + 6);
        const float2 a2 = *(const float2*)(fp + 8);
        const float4 b0 = *(const float4*)(fp + 12);
        const float2 b1 = *(const float2*)(fp + 18);
        const float2 b2 = *(const float2*)(fp + 20);
        {
            const bool act_ = base < len;
            const float f0_=a0.x, f1_=a0.y, f2_=a0.z, f3_=a0.w;
            const float fe0_=__expf(f0_), fe1_=__expf(f1_);
            const float fe2_=__expf(f2_), fe3_=__expf(f3_);
            #pragma unroll
            for (int j = 0; j < 4; ++j) {
                const float u0 = seg0 ? e4[0] : E[0*4+j];
                const float u1 = seg0 ? e4[1] : E[1*4+j];
                const float u2 = seg0 ? e4[2] : E[2*4+j];
                const float u3 = seg0 ? e4[3] : E[3*4+j];
                P[0*4+j] = act_ ? fe0_*u0 : P[0*4+j];
                P[1*4+j] = act_ ? fe1_*u1 : P[1*4+j];
                P[2*4+j] = act_ ? fe2_*u2 : P[2*4+j];
                P[3*4+j] = act_ ? fe3_*u3 : P[3*4+j];
            }
            const float lut_ = sT[t0 * 6 + pv0];
            const float em_  = (t0 & 2) ? ((t0 & 1) ? f3_ : f2_)
                                        : ((t0 & 1) ? f1_ : f0_);
            gold += act_ ? (lut_ + em_) : 0.f;
        }
        STEP(base+1, a1.x, a1.y, a2.x, a2.y, t1, t0);
        STEP(base+2, b0.x, b0.y, b0.z, b0.w, t2, t1);
        STEP(base+3, b1.x, b1.y, b2.x, b2.y, t3, t2);
        RENORM16(P, mex);
        pv = t3;
    }

    // ---- remaining 28 steps, 4 per iteration ----
    for (int p = 1; p < 8; ++p) {
        const int4 tq = *(const int4*)(tbp + p * 4);
        const int t0 = tq.x & 3, t1 = tq.y & 3, t2 = tq.z & 3, t3 = tq.w & 3;
        const float* q = fp + p * 24;
        const float4 a0 = *(const float4*)(q + 0);
        const float2 a1 = *(const float2*)(q + 6);
        const float2 a2 = *(const float2*)(q + 8);
        const float4 b0 = *(const float4*)(q + 12);
        const float2 b1 = *(const float2*)(q + 18);
        const float2 b2 = *(const float2*)(q + 20);
        const int s0 = base + p * 4;
        STEP(s0+0, a0.x, a0.y, a0.z, a0.w, t0, pv);
        STEP(s0+1, a1.x, a1.y, a2.x, a2.y, t1, t0);
        STEP(s0+2, b0.x, b0.y, b0.z, b0.w, t2, t1);
        STEP(s0+3, b1.x, b1.y, b2.x, b2.y, t3, t2);
        RENORM16(P, mex);
        pv = t3;
    }

    // terminal gold: lane owning step len-1 adds trans[STOP][last_tag]
    {
        const unsigned dl = (unsigned)(len - 1 - base);
        if (dl < 32u) gold += sT[30 + (tbp[dl] & 3)];
    }

    // ---- ordered combine within 16-lane group: P <- P_{c+k} * P_c ----
    #pragma unroll
    for (int k = 1; k <= 8; k <<= 1) {
        float Q[16];
        #pragma unroll
        for (int z = 0; z < 16; ++z) Q[z] = __shfl_down(P[z], k, 16);
        const int mq = __shfl_down(mex, k, 16);
        float N[16];
        #pragma unroll
        for (int i = 0; i < 4; ++i)
            #pragma unroll
            for (int j = 0; j < 4; ++j)
                N[i*4+j] = fmaf(Q[i*4+0], P[0*4+j], fmaf(Q[i*4+1], P[1*4+j],
                           fmaf(Q[i*4+2], P[2*4+j], Q[i*4+3] * P[3*4+j])));
        #pragma unroll
        for (int z = 0; z < 16; ++z) P[z] = N[z];
        mex += mq;
        RENORM16(P, mex);
    }

    // gold: sum across the 16-lane group
    #pragma unroll
    for (int k = 1; k <= 8; k <<= 1)
        gold += __shfl_xor(gold, k, 16);

    // group-lane 0: columns of P all equal alpha (e4 folded into segment 0)
    const float dot = fmaf(e5[0], P[0], fmaf(e5[1], P[4],
                      fmaf(e5[2], P[8], e5[3] * P[12])));
    const float logz = fmaf((float)mex, LN2F, __logf(dot));
    if (c == 0)
        partials[b] = logz - gold;
}

__global__ __launch_bounds__(256) void k_reduce(const float* __restrict__ partials,
                                               float* __restrict__ out)
{
    __shared__ float sh[256];
    const int t = threadIdx.x;
    float s = 0.f;
    #pragma unroll
    for (int j = 0; j < 32; ++j) s += partials[t + 256 * j];
    sh[t] = s;
    __syncthreads();
    #pragma unroll
    for (int d = 128; d > 0; d >>= 1) {
        if (t < d) sh[t] += sh[t + d];
        __syncthreads();
    }
    if (t == 0) out[0] = sh[0] * (1.0f / 8192.0f);
}

extern "C" void kernel_launch(void* const* d_in, const int* in_sizes, int n_in,
                              void* d_out, int out_size, void* d_ws, size_t ws_size,
                              hipStream_t stream) {
    const float* feats = (const float*)d_in[0];
    const float* trans = (const float*)d_in[1];
    const int*   tags  = (const int*)d_in[2];
    const int*   lens  = (const int*)d_in[3];
    float* out = (float*)d_out;
    float* partials = (float*)d_ws;        // 8192 floats

    crf_tree<<<BB / 16, 256, 0, stream>>>(feats, trans, tags, lens, partials);
    k_reduce<<<1, 256, 0, stream>>>(partials, out);
}

// Round 13
// 32.161 us; speedup vs baseline: 2.1365x; 1.4377x over previous
//
#include <hip/hip_runtime.h>

// CRF NLL forward, B=8192, L=512, T=6 (4 real states + START/STOP).
// 64-lane wave = 2 batches x 32 lanes. Lane (g,c) builds the ordered product
// of M_l = diag(exp(feat_l)) * E over steps [16c, 16c+16) of batch g
// (scaled-probability domain, power-of-2 renorm every 4 steps, exponent in an
// int). ALL 24 feat loads + tags issued up front (MLP; R12's in-loop loads
// were latency-bound at 2 waves/SIMD). Combine: 4 ordered __shfl_down rounds
// at width=32 (k=1,2,4,8; renorm after k=2,8 only) + final k=16 rank-1
// mat-vec (segment-0 e4 fold makes lane 0's columns all equal alpha).
// Gold fused per-lane, shfl_xor width-32 reduced. 4096 waves = 4/SIMD.

#define BB 8192
#define LL 512
#define LN2F 0.69314718055994530942f

__device__ __forceinline__ float uniformf(float x) {
    return __uint_as_float(__builtin_amdgcn_readfirstlane(__float_as_uint(x)));
}

#define RENORM16(P, MEX)                                                \
  do {                                                                  \
    float m_ = fmaxf(P[0], P[1]);                                       \
    _Pragma("unroll") for (int z_ = 2; z_ < 16; ++z_) m_ = fmaxf(m_, P[z_]); \
    const int ee_ = (int)((__float_as_uint(m_) >> 23) & 255) - 127;     \
    const float sc_ = __uint_as_float((unsigned)(127 - ee_) << 23);     \
    _Pragma("unroll") for (int z_ = 0; z_ < 16; ++z_) P[z_] *= sc_;     \
    MEX += ee_;                                                         \
  } while (0)

// One step at absolute index ABS: P <- diag(exp(f)) * E * P (masked), + gold.
#define STEP(ABS, F0, F1, F2, F3, TG, PV)                               \
  do {                                                                  \
    const bool act_ = (ABS) < len;                                      \
    const float f0_=(F0), f1_=(F1), f2_=(F2), f3_=(F3);                 \
    const float fe0_=__expf(f0_), fe1_=__expf(f1_);                     \
    const float fe2_=__expf(f2_), fe3_=__expf(f3_);                     \
    _Pragma("unroll")                                                   \
    for (int j = 0; j < 4; ++j) {                                       \
      const float c0_=P[0*4+j], c1_=P[1*4+j], c2_=P[2*4+j], c3_=P[3*4+j]; \
      const float t0_ = fmaf(E[0], c0_, fmaf(E[1], c1_, fmaf(E[2], c2_, E[3] *c3_))); \
      const float t1_ = fmaf(E[4], c0_, fmaf(E[5], c1_, fmaf(E[6], c2_, E[7] *c3_))); \
      const float t2_ = fmaf(E[8], c0_, fmaf(E[9], c1_, fmaf(E[10],c2_, E[11]*c3_))); \
      const float t3_ = fmaf(E[12],c0_, fmaf(E[13],c1_, fmaf(E[14],c2_, E[15]*c3_))); \
      P[0*4+j] = act_ ? fe0_*t0_ : P[0*4+j];                            \
      P[1*4+j] = act_ ? fe1_*t1_ : P[1*4+j];                            \
      P[2*4+j] = act_ ? fe2_*t2_ : P[2*4+j];                            \
      P[3*4+j] = act_ ? fe3_*t3_ : P[3*4+j];                            \
    }                                                                   \
    const float lut_ = sT[(TG) * 6 + (PV)];                             \
    const float em_  = ((TG) & 2) ? (((TG) & 1) ? f3_ : f2_)            \
                                  : (((TG) & 1) ? f1_ : f0_);           \
    gold += act_ ? (lut_ + em_) : 0.f;                                  \
  } while (0)

// step s (1..15): even s uses F0[s/2]; odd s uses F1[s/2],F2[s/2]
#define TGAT(S)  ((int)((tpk >> (2*(S))) & 3u))
#define STEPE(S) STEP(base+(S), F0[(S)/2].x, F0[(S)/2].y, F0[(S)/2].z, F0[(S)/2].w, TGAT(S), TGAT((S)-1))
#define STEPO(S) STEP(base+(S), F1[(S)/2].x, F1[(S)/2].y, F2[(S)/2].x, F2[(S)/2].y, TGAT(S), TGAT((S)-1))

__global__ __launch_bounds__(256, 4) void crf_tree(
    const float* __restrict__ feats,
    const float* __restrict__ trans,
    const int*   __restrict__ tags,
    const int*   __restrict__ lens,
    float* __restrict__ partials)
{
    __shared__ float sT[36];

    const int tid  = threadIdx.x;
    const int lane = tid & 63;
    const int wv   = tid >> 6;
    const int g    = lane >> 5;        // batch sub-index within wave (0..1)
    const int c    = lane & 31;        // segment index (0..31), 16 steps each
    const int b    = blockIdx.x * 8 + wv * 2 + g;

    if (tid < 36) sT[tid] = trans[tid];
    __syncthreads();

    // wave-uniform transition constants (SGPR via readfirstlane)
    float E[16], e4[4], e5[4];
    #pragma unroll
    for (int i = 0; i < 16; ++i)
        E[i] = uniformf(__expf(sT[(i >> 2) * 6 + (i & 3)]));
    #pragma unroll
    for (int i = 0; i < 4; ++i) {
        e4[i] = uniformf(__expf(sT[i * 6 + 4]));   // exp(trans[i][START])
        e5[i] = uniformf(__expf(sT[30 + i]));      // exp(trans[STOP][i])
    }

    const int len  = lens[b];
    const int base = c * 16;
    const bool seg0 = (c == 0);

    const float* fp  = feats + (size_t)b * (LL * 6) + (size_t)base * 6;
    const int*   tbp = tags  + (size_t)b * LL + base;
    const int pv0 = seg0 ? 4 : (tbp[-1] & 3);

    // ---- ALL loads issued up front (24 feat + 4 tag loads in flight) ----
    float4 F0[8]; float2 F1[8], F2[8];
    #pragma unroll
    for (int p = 0; p < 8; ++p) {
        const float* q = fp + p * 12;
        F0[p] = *(const float4*)(q);
        F1[p] = *(const float2*)(q + 6);
        F2[p] = *(const float2*)(q + 8);
    }
    unsigned tpk = 0;                      // 16 tags packed 2b each
    #pragma unroll
    for (int q = 0; q < 4; ++q) {
        const int4 t = *(const int4*)(tbp + q * 4);
        tpk |= (unsigned)(t.x & 3) << (2*(q*4+0));
        tpk |= (unsigned)(t.y & 3) << (2*(q*4+1));
        tpk |= (unsigned)(t.z & 3) << (2*(q*4+2));
        tpk |= (unsigned)(t.w & 3) << (2*(q*4+3));
    }

    float P[16];
    #pragma unroll
    for (int z = 0; z < 16; ++z) P[z] = (z % 5 == 0) ? 1.f : 0.f;
    int   mex  = 0;
    float gold = 0.f;

    // ---- step 0 specialized: P was identity; seg0 folds e4 (START) ----
    {
        const bool act_ = base < len;
        const float f0_=F0[0].x, f1_=F0[0].y, f2_=F0[0].z, f3_=F0[0].w;
        const float fe0_=__expf(f0_), fe1_=__expf(f1_);
        const float fe2_=__expf(f2_), fe3_=__expf(f3_);
        #pragma unroll
        for (int j = 0; j < 4; ++j) {
            const float u0 = seg0 ? e4[0] : E[0*4+j];
            const float u1 = seg0 ? e4[1] : E[1*4+j];
            const float u2 = seg0 ? e4[2] : E[2*4+j];
            const float u3 = seg0 ? e4[3] : E[3*4+j];
            P[0*4+j] = act_ ? fe0_*u0 : P[0*4+j];
            P[1*4+j] = act_ ? fe1_*u1 : P[1*4+j];
            P[2*4+j] = act_ ? fe2_*u2 : P[2*4+j];
            P[3*4+j] = act_ ? fe3_*u3 : P[3*4+j];
        }
        const int t0 = TGAT(0);
        const float lut_ = sT[t0 * 6 + pv0];
        const float em_  = (t0 & 2) ? ((t0 & 1) ? f3_ : f2_)
                                    : ((t0 & 1) ? f1_ : f0_);
        gold += act_ ? (lut_ + em_) : 0.f;
    }
    STEPO(1);  STEPE(2);  STEPO(3);  RENORM16(P, mex);
    STEPE(4);  STEPO(5);  STEPE(6);  STEPO(7);  RENORM16(P, mex);
    STEPE(8);  STEPO(9);  STEPE(10); STEPO(11); RENORM16(P, mex);
    STEPE(12); STEPO(13); STEPE(14); STEPO(15); RENORM16(P, mex);

    // terminal gold: lane owning step len-1 adds trans[STOP][last_tag]
    {
        const unsigned dl = (unsigned)(len - 1 - base);
        if (dl < 16u) gold += sT[30 + (int)((tpk >> (2*dl)) & 3u)];
    }

    // ---- ordered combine width 32: P <- P_{c+k} * P_c, k=1,2,4,8 ----
    // renorm only after k=2 and k=8 (growth <= 2^10 between; exact pow2)
    #pragma unroll
    for (int k = 1; k <= 8; k <<= 1) {
        float Q[16];
        #pragma unroll
        for (int z = 0; z < 16; ++z) Q[z] = __shfl_down(P[z], k, 32);
        const int mq = __shfl_down(mex, k, 32);
        float N[16];
        #pragma unroll
        for (int i = 0; i < 4; ++i)
            #pragma unroll
            for (int j = 0; j < 4; ++j)
                N[i*4+j] = fmaf(Q[i*4+0], P[0*4+j], fmaf(Q[i*4+1], P[1*4+j],
                           fmaf(Q[i*4+2], P[2*4+j], Q[i*4+3] * P[3*4+j])));
        #pragma unroll
        for (int z = 0; z < 16; ++z) P[z] = N[z];
        mex += mq;
        if (k == 2 || k == 8) RENORM16(P, mex);
    }

    // ---- final k=16: rank-1 -> mat-vec (alpha = column 0) ----
    float al0, al1, al2, al3;
    {
        float Q[16];
        #pragma unroll
        for (int z = 0; z < 16; ++z) Q[z] = __shfl_down(P[z], 16, 32);
        const int mq = __shfl_down(mex, 16, 32);
        al0 = fmaf(Q[0], P[0], fmaf(Q[1], P[4], fmaf(Q[2], P[8], Q[3] *P[12])));
        al1 = fmaf(Q[4], P[0], fmaf(Q[5], P[4], fmaf(Q[6], P[8], Q[7] *P[12])));
        al2 = fmaf(Q[8], P[0], fmaf(Q[9], P[4], fmaf(Q[10],P[8], Q[11]*P[12])));
        al3 = fmaf(Q[12],P[0], fmaf(Q[13],P[4], fmaf(Q[14],P[8], Q[15]*P[12])));
        mex += mq;
    }

    // gold: sum across the 32-lane group
    #pragma unroll
    for (int k = 1; k <= 16; k <<= 1)
        gold += __shfl_xor(gold, k, 32);

    const float dot = fmaf(e5[0], al0, fmaf(e5[1], al1,
                      fmaf(e5[2], al2, e5[3] * al3)));
    const float logz = fmaf((float)mex, LN2F, __logf(dot));
    if (c == 0)
        partials[b] = logz - gold;
}

__global__ __launch_bounds__(256) void k_reduce(const float* __restrict__ partials,
                                               float* __restrict__ out)
{
    __shared__ float sh[256];
    const int t = threadIdx.x;
    float s = 0.f;
    #pragma unroll
    for (int j = 0; j < 32; ++j) s += partials[t + 256 * j];
    sh[t] = s;
    __syncthreads();
    #pragma unroll
    for (int d = 128; d > 0; d >>= 1) {
        if (t < d) sh[t] += sh[t + d];
        __syncthreads();
    }
    if (t == 0) out[0] = sh[0] * (1.0f / 8192.0f);
}

extern "C" void kernel_launch(void* const* d_in, const int* in_sizes, int n_in,
                              void* d_out, int out_size, void* d_ws, size_t ws_size,
                              hipStream_t stream) {
    const float* feats = (const float*)d_in[0];
    const float* trans = (const float*)d_in[1];
    const int*   tags  = (const int*)d_in[2];
    const int*   lens  = (const int*)d_in[3];
    float* out = (float*)d_out;
    float* partials = (float*)d_ws;        // 8192 floats

    crf_tree<<<BB / 8, 256, 0, stream>>>(feats, trans, tags, lens, partials);
    k_reduce<<<1, 256, 0, stream>>>(partials, out);
}